// Round 9
// baseline (1417.143 us; speedup 1.0000x reference)
//
#include <hip/hip_runtime.h>
#include <hip/hip_bf16.h>

// AdaConv2d: per-sample conv, kernel = base * mask[label[b]] (oc-indep mask).
// B=64, IC=OC=64, H=W=112, 3x3, pad 1. fp32 in/out.
//
// Round 8: round 7 fetched 1.2 GB HBM (11x over-fetch) because Xt[y][x][64ic]
// puts a pixel's 64 channels in one 128B line while each ck-pass reads only
// 32B of it -> 4x line waste -> 95KB L1 footprint -> 9-tap reuse missed L1/L2.
// New layout: per-chunk planes Xt[b][ck][y][x][16ic] -> full line use, 24KB
// per-ck block footprint (L1-resident), taps hit L1. Main kernel unchanged
// otherwise (LDS-free implicit GEMM, mfma_f32_32x32x16_bf16).

#define HH 112
#define WW 112
#define ICn 64
#define OCn 64
#define FUSE_EPOCH 9
#define NPIX (HH * WW)
#define YP 114

typedef __attribute__((ext_vector_type(8)))  short  short8;
typedef __attribute__((ext_vector_type(8)))  unsigned short bf8;
typedef __attribute__((ext_vector_type(4)))  unsigned short bf4;
typedef __attribute__((ext_vector_type(16))) float  f32x16;

#define XT_ELEMS ((size_t)64 * 4 * YP * YP * 16)
#define XT_BYTES (XT_ELEMS * 2)
#define WF_BYTES ((size_t)4 * 64 * 576 * 2)

static __device__ __forceinline__ unsigned short f2bf(float v) {
    __hip_bfloat16 hb = __float2bfloat16(v);
    return *reinterpret_cast<unsigned short*>(&hb);
}

// ---------------- fused weights: wf[d][oc][ck][tap][ic'] ----------------
__global__ __launch_bounds__(256)
void fuse_w_kernel(const float* __restrict__ kb, const float* __restrict__ km,
                   unsigned short* __restrict__ wf)
{
    int idx = blockIdx.x * 256 + threadIdx.x;
    if (idx >= 4 * 64 * 576) return;
    int ic_ = idx & 15;
    int r = idx >> 4;
    int t = r % 9; r /= 9;
    int ch = r & 3; r >>= 2;
    int oc = r & 63;
    int d = r >> 6;
    int ic = ch * 16 + ic_;
    wf[idx] = f2bf(kb[(oc * ICn + ic) * 9 + t] * km[(d * ICn + ic) * 9 + t]);
}

// ---------------- zero the halo of each (b,ck) plane ----------------
__global__ __launch_bounds__(256)
void pad_zero_kernel(unsigned short* __restrict__ Xt)
{
    const int plane = blockIdx.x;   // 0..255 = b*4+ck
    const int tid = threadIdx.x;
    const size_t base = (size_t)plane * YP * YP * 16;
    const bf8 z = bf8{0,0,0,0,0,0,0,0};
    // rows y=0 and y=113 (full): YP*16 elems each
    for (int i = tid; i < YP * 2; i += 256) {
        *reinterpret_cast<bf8*>(Xt + base + (size_t)i * 8) = z;
        *reinterpret_cast<bf8*>(Xt + base + (size_t)113 * YP * 16 + (size_t)i * 8) = z;
    }
    // cols x=0 and x=113, rows 1..112: 2 bf8 per pixel
    for (int i = tid; i < 112 * 2 * 2; i += 256) {
        int j = i & 1, col = (i >> 1) & 1, yp = 1 + (i >> 2);
        size_t off = base + ((size_t)yp * YP + col * 113) * 16 + (size_t)j * 8;
        *reinterpret_cast<bf8*>(Xt + off) = z;
    }
}

// ---- transpose x[b][ic][y][x] fp32 -> Xt[b][ic/16][y+1][x+1][ic%16] bf16 ----
__global__ __launch_bounds__(256, 4)
void transpose_kernel(const float* __restrict__ x, unsigned short* __restrict__ Xt)
{
    __shared__ unsigned short T[56][68];
    const int tid = threadIdx.x;
    const int xh = blockIdx.x;      // 0..1 -> x0 = 0,56
    const int y  = blockIdx.y;      // 0..111
    const int b  = blockIdx.z;      // 0..63
    const int x0 = xh * 56;

    for (int i = tid; i < 64 * 14; i += 256) {       // 64 ic x 14 float4
        int ic = i / 14, c4 = i - ic * 14;
        const float4* p = reinterpret_cast<const float4*>(
            x + (((size_t)b * ICn + ic) * HH + y) * WW + x0 + c4 * 4);
        float4 v = *p;
        T[c4 * 4 + 0][ic] = f2bf(v.x);
        T[c4 * 4 + 1][ic] = f2bf(v.y);
        T[c4 * 4 + 2][ic] = f2bf(v.z);
        T[c4 * 4 + 3][ic] = f2bf(v.w);
    }
    __syncthreads();
    for (int i = tid; i < 56 * 16; i += 256) {       // 56 x  x 16 bf4
        int xx = i >> 4, k = i & 15;
        bf4 w = *reinterpret_cast<bf4*>(&T[xx][k * 4]);
        int ck = k >> 2, q = k & 3;
        *reinterpret_cast<bf4*>(
            Xt + ((((size_t)b * 4 + ck) * YP + y + 1) * YP + (x0 + xx + 1)) * 16 + q * 4) = w;
    }
}

// ---------------- main: implicit GEMM, no LDS ----------------
__global__ __launch_bounds__(256, 4)
void adaconv_main(const unsigned short* __restrict__ Xt,
                  const unsigned short* __restrict__ wf,
                  const int* __restrict__ label,
                  const int* __restrict__ epoch,
                  float* __restrict__ out)
{
    const int tid  = threadIdx.x;
    const int b    = blockIdx.y;
    const int w    = tid >> 6;
    const int lane = tid & 63;
    const int ln   = lane & 31;
    const int h    = lane >> 5;

    int d = (epoch[0] >= FUSE_EPOCH) ? 0 : label[b];
    d &= 3;

    f32x16 acc[2][4];
    #pragma unroll
    for (int m = 0; m < 2; ++m)
        #pragma unroll
        for (int rj = 0; rj < 4; ++rj)
            #pragma unroll
            for (int k = 0; k < 16; ++k) acc[m][rj][k] = 0.f;

    int yy[4], xx[4];
    bool valid[4];
    #pragma unroll
    for (int rj = 0; rj < 4; ++rj) {
        int p = blockIdx.x * 512 + w * 128 + rj * 32 + ln;
        valid[rj] = (p < NPIX);
        int pc = valid[rj] ? p : (NPIX - 1);
        yy[rj] = pc / WW;
        xx[rj] = pc - yy[rj] * WW;
    }

    const bf8* Wv = reinterpret_cast<const bf8*>(wf) + (size_t)d * 64 * 72;
    // Wv index: (oc*4 + ck)*18 + t*2 + h

    #pragma unroll
    for (int ck = 0; ck < 4; ++ck) {
        const unsigned plane = ((unsigned)b * 4 + ck) * (YP * YP);
        #pragma unroll
        for (int kh = 0; kh < 3; ++kh) {
            #pragma unroll
            for (int kw = 0; kw < 3; ++kw) {
                const int t = kh * 3 + kw;
                short8 a0 = *reinterpret_cast<const short8*>(&Wv[(ln * 4 + ck) * 18 + t * 2 + h]);
                short8 a1 = *reinterpret_cast<const short8*>(&Wv[((ln + 32) * 4 + ck) * 18 + t * 2 + h]);
                #pragma unroll
                for (int rj = 0; rj < 4; ++rj) {
                    unsigned off = ((plane + (unsigned)(yy[rj] + kh) * YP + (unsigned)(xx[rj] + kw)) << 4)
                                   + (h << 3);
                    short8 bb = *reinterpret_cast<const short8*>(Xt + off);
                    acc[0][rj] = __builtin_amdgcn_mfma_f32_32x32x16_bf16(a0, bb, acc[0][rj], 0, 0, 0);
                    acc[1][rj] = __builtin_amdgcn_mfma_f32_32x32x16_bf16(a1, bb, acc[1][rj], 0, 0, 0);
                }
            }
        }
    }

    // store: oc = m*32 + (reg&3) + 8*(reg>>2) + 4*h ; col = pixel p
    #pragma unroll
    for (int m = 0; m < 2; ++m) {
        #pragma unroll
        for (int rj = 0; rj < 4; ++rj) {
            if (!valid[rj]) continue;
            int p = blockIdx.x * 512 + w * 128 + rj * 32 + ln;
            float* ob = out + ((size_t)b * OCn + m * 32 + 4 * h) * NPIX + p;
            #pragma unroll
            for (int reg = 0; reg < 16; ++reg) {
                int row = (reg & 3) + 8 * (reg >> 2);
                ob[(size_t)row * NPIX] = acc[m][rj][reg];
            }
        }
    }
}

// ---------------- fallback (round-5 structure, no ws) ----------------
#define ICP 24
#define WSTRIDE 152
__global__ __launch_bounds__(256, 2)
void adaconv_fallback(const float* __restrict__ x,
                      const float* __restrict__ kb,
                      const float* __restrict__ km,
                      const int* __restrict__ label,
                      const int* __restrict__ epoch,
                      float* __restrict__ out)
{
    __shared__ unsigned short Xs[18][34][ICP];
    __shared__ unsigned short Ws[64][WSTRIDE];

    const int tid = threadIdx.x;
    const int b   = blockIdx.y;
    const int bx  = blockIdx.x & 3;
    const int byy = blockIdx.x >> 2;
    const int x0 = bx * 32, y0 = byy * 16;

    int d = (epoch[0] >= FUSE_EPOCH) ? 0 : label[b];
    d &= 3;

    const int w    = tid >> 6;
    const int lane = tid & 63;
    const int ln   = lane & 31;
    const int h    = lane >> 5;

    f32x16 acc[2][4];
    #pragma unroll
    for (int m = 0; m < 2; ++m)
        #pragma unroll
        for (int j = 0; j < 4; ++j)
            #pragma unroll
            for (int k = 0; k < 16; ++k) acc[m][j][k] = 0.f;

    const float* xb = x + (size_t)b * ICn * HH * WW;

    for (int ck = 0; ck < 4; ++ck) {
        const int icb = ck * 16;
        __syncthreads();
        for (int idx = tid; idx < 18 * 34 * 16; idx += 256) {
            int ic  = idx / 612;
            int rem = idx - ic * 612;
            int r   = rem / 34;
            int c   = rem - r * 34;
            int gy = y0 - 1 + r, gx = x0 - 1 + c;
            float v = 0.f;
            if ((unsigned)gy < HH && (unsigned)gx < WW)
                v = xb[(size_t)(icb + ic) * (HH * WW) + gy * WW + gx];
            Xs[r][c][ic] = f2bf(v);
        }
        for (int i = tid; i < 9216; i += 256) {
            int ic_ = i & 15;
            int tt  = (i >> 4) % 9;
            int oc  = i / 144;
            int ic  = icb + ic_;
            Ws[oc][tt * 16 + ic_] = f2bf(kb[(oc * ICn + ic) * 9 + tt] * km[(d * ICn + ic) * 9 + tt]);
        }
        __syncthreads();
        #pragma unroll
        for (int kh = 0; kh < 3; ++kh)
            #pragma unroll
            for (int kw = 0; kw < 3; ++kw) {
                const int t = kh * 3 + kw;
                short8 a0 = *reinterpret_cast<const short8*>(&Ws[ln][t * 16 + h * 8]);
                short8 a1 = *reinterpret_cast<const short8*>(&Ws[32 + ln][t * 16 + h * 8]);
                #pragma unroll
                for (int rj = 0; rj < 4; ++rj) {
                    short8 bb = *reinterpret_cast<const short8*>(&Xs[4 * w + rj + kh][ln + kw][h * 8]);
                    acc[0][rj] = __builtin_amdgcn_mfma_f32_32x32x16_bf16(a0, bb, acc[0][rj], 0, 0, 0);
                    acc[1][rj] = __builtin_amdgcn_mfma_f32_32x32x16_bf16(a1, bb, acc[1][rj], 0, 0, 0);
                }
            }
    }

    const int xg = x0 + ln;
    if (xg < WW) {
        #pragma unroll
        for (int m = 0; m < 2; ++m)
            #pragma unroll
            for (int rj = 0; rj < 4; ++rj) {
                const int yg = y0 + 4 * w + rj;
                #pragma unroll
                for (int reg = 0; reg < 16; ++reg) {
                    const int row = (reg & 3) + 8 * (reg >> 2) + 4 * h;
                    out[(((size_t)b * OCn + m * 32 + row) * HH + yg) * WW + xg] = acc[m][rj][reg];
                }
            }
    }
}

extern "C" void kernel_launch(void* const* d_in, const int* in_sizes, int n_in,
                              void* d_out, int out_size, void* d_ws, size_t ws_size,
                              hipStream_t stream) {
    const float* x  = (const float*)d_in[0];
    const float* kb = (const float*)d_in[1];
    const float* km = (const float*)d_in[2];
    const int*   lb = (const int*)d_in[3];
    const int*   ep = (const int*)d_in[4];
    float* out = (float*)d_out;

    if (ws_size >= XT_BYTES + WF_BYTES) {
        unsigned short* Xt = (unsigned short*)d_ws;
        unsigned short* wf = (unsigned short*)((char*)d_ws + XT_BYTES);
        fuse_w_kernel<<<(4 * 64 * 576 + 255) / 256, 256, 0, stream>>>(kb, km, wf);
        pad_zero_kernel<<<256, 256, 0, stream>>>(Xt);
        transpose_kernel<<<dim3(2, HH, 64), 256, 0, stream>>>(x, Xt);
        adaconv_main<<<dim3(25, 64), 256, 0, stream>>>(Xt, wf, lb, ep, out);
    } else {
        adaconv_fallback<<<dim3(28, 64), 256, 0, stream>>>(x, kb, km, lb, ep, out);
    }
}

// Round 10
// 233.272 us; speedup vs baseline: 6.0751x; 6.0751x over previous
//
#include <hip/hip_runtime.h>
#include <hip/hip_bf16.h>

// AdaConv2d: per-sample conv, kernel = base * mask[label[b]] (oc-indep mask).
// B=64, IC=OC=64, H=W=112, 3x3, pad 1. fp32 in/out.
//
// Round 9: revert round-8's __launch_bounds__(256,4) on the main kernel ->
// it capped VGPR+AGPR at 128, spilling the 128-reg accumulator to scratch
// (VGPR_Count 64, WRITE_SIZE 3.5 GB = 288 MFMA x 8KB acc round-trips/block).
// Keep the per-chunk plane layout Xt[b][ck][y][x][16ic] from round 8 (fixes
// round 7's 11x HBM over-fetch: full 128B line use, 24KB/block/ck footprint).

#define HH 112
#define WW 112
#define ICn 64
#define OCn 64
#define FUSE_EPOCH 9
#define NPIX (HH * WW)
#define YP 114

typedef __attribute__((ext_vector_type(8)))  short  short8;
typedef __attribute__((ext_vector_type(8)))  unsigned short bf8;
typedef __attribute__((ext_vector_type(4)))  unsigned short bf4;
typedef __attribute__((ext_vector_type(16))) float  f32x16;

#define XT_ELEMS ((size_t)64 * 4 * YP * YP * 16)
#define XT_BYTES (XT_ELEMS * 2)
#define WF_BYTES ((size_t)4 * 64 * 576 * 2)

static __device__ __forceinline__ unsigned short f2bf(float v) {
    __hip_bfloat16 hb = __float2bfloat16(v);
    return *reinterpret_cast<unsigned short*>(&hb);
}

// ---------------- fused weights: wf[d][oc][ck][tap][ic'] ----------------
__global__ __launch_bounds__(256)
void fuse_w_kernel(const float* __restrict__ kb, const float* __restrict__ km,
                   unsigned short* __restrict__ wf)
{
    int idx = blockIdx.x * 256 + threadIdx.x;
    if (idx >= 4 * 64 * 576) return;
    int ic_ = idx & 15;
    int r = idx >> 4;
    int t = r % 9; r /= 9;
    int ch = r & 3; r >>= 2;
    int oc = r & 63;
    int d = r >> 6;
    int ic = ch * 16 + ic_;
    wf[idx] = f2bf(kb[(oc * ICn + ic) * 9 + t] * km[(d * ICn + ic) * 9 + t]);
}

// ---------------- zero the halo of each (b,ck) plane ----------------
__global__ __launch_bounds__(256)
void pad_zero_kernel(unsigned short* __restrict__ Xt)
{
    const int plane = blockIdx.x;   // 0..255 = b*4+ck
    const int tid = threadIdx.x;
    const size_t base = (size_t)plane * YP * YP * 16;
    const bf8 z = bf8{0,0,0,0,0,0,0,0};
    // rows y=0 and y=113 (full): YP*16 elems each
    for (int i = tid; i < YP * 2; i += 256) {
        *reinterpret_cast<bf8*>(Xt + base + (size_t)i * 8) = z;
        *reinterpret_cast<bf8*>(Xt + base + (size_t)113 * YP * 16 + (size_t)i * 8) = z;
    }
    // cols x=0 and x=113, rows 1..112: 2 bf8 per pixel
    for (int i = tid; i < 112 * 2 * 2; i += 256) {
        int j = i & 1, col = (i >> 1) & 1, yp = 1 + (i >> 2);
        size_t off = base + ((size_t)yp * YP + col * 113) * 16 + (size_t)j * 8;
        *reinterpret_cast<bf8*>(Xt + off) = z;
    }
}

// ---- transpose x[b][ic][y][x] fp32 -> Xt[b][ic/16][y+1][x+1][ic%16] bf16 ----
__global__ __launch_bounds__(256, 4)
void transpose_kernel(const float* __restrict__ x, unsigned short* __restrict__ Xt)
{
    __shared__ unsigned short T[56][68];
    const int tid = threadIdx.x;
    const int xh = blockIdx.x;      // 0..1 -> x0 = 0,56
    const int y  = blockIdx.y;      // 0..111
    const int b  = blockIdx.z;      // 0..63
    const int x0 = xh * 56;

    for (int i = tid; i < 64 * 14; i += 256) {       // 64 ic x 14 float4
        int ic = i / 14, c4 = i - ic * 14;
        const float4* p = reinterpret_cast<const float4*>(
            x + (((size_t)b * ICn + ic) * HH + y) * WW + x0 + c4 * 4);
        float4 v = *p;
        T[c4 * 4 + 0][ic] = f2bf(v.x);
        T[c4 * 4 + 1][ic] = f2bf(v.y);
        T[c4 * 4 + 2][ic] = f2bf(v.z);
        T[c4 * 4 + 3][ic] = f2bf(v.w);
    }
    __syncthreads();
    for (int i = tid; i < 56 * 16; i += 256) {       // 56 x  x 16 bf4
        int xx = i >> 4, k = i & 15;
        bf4 w = *reinterpret_cast<bf4*>(&T[xx][k * 4]);
        int ck = k >> 2, q = k & 3;
        *reinterpret_cast<bf4*>(
            Xt + ((((size_t)b * 4 + ck) * YP + y + 1) * YP + (x0 + xx + 1)) * 16 + q * 4) = w;
    }
}

// ---------------- main: implicit GEMM, no LDS ----------------
__global__ __launch_bounds__(256, 2)
void adaconv_main(const unsigned short* __restrict__ Xt,
                  const unsigned short* __restrict__ wf,
                  const int* __restrict__ label,
                  const int* __restrict__ epoch,
                  float* __restrict__ out)
{
    const int tid  = threadIdx.x;
    const int b    = blockIdx.y;
    const int w    = tid >> 6;
    const int lane = tid & 63;
    const int ln   = lane & 31;
    const int h    = lane >> 5;

    int d = (epoch[0] >= FUSE_EPOCH) ? 0 : label[b];
    d &= 3;

    f32x16 acc[2][4];
    #pragma unroll
    for (int m = 0; m < 2; ++m)
        #pragma unroll
        for (int rj = 0; rj < 4; ++rj)
            #pragma unroll
            for (int k = 0; k < 16; ++k) acc[m][rj][k] = 0.f;

    int yy[4], xx[4];
    bool valid[4];
    #pragma unroll
    for (int rj = 0; rj < 4; ++rj) {
        int p = blockIdx.x * 512 + w * 128 + rj * 32 + ln;
        valid[rj] = (p < NPIX);
        int pc = valid[rj] ? p : (NPIX - 1);
        yy[rj] = pc / WW;
        xx[rj] = pc - yy[rj] * WW;
    }

    const bf8* Wv = reinterpret_cast<const bf8*>(wf) + (size_t)d * 64 * 72;
    // Wv index: (oc*4 + ck)*18 + t*2 + h

    #pragma unroll
    for (int ck = 0; ck < 4; ++ck) {
        const unsigned plane = ((unsigned)b * 4 + ck) * (YP * YP);
        #pragma unroll
        for (int kh = 0; kh < 3; ++kh) {
            #pragma unroll
            for (int kw = 0; kw < 3; ++kw) {
                const int t = kh * 3 + kw;
                short8 a0 = *reinterpret_cast<const short8*>(&Wv[(ln * 4 + ck) * 18 + t * 2 + h]);
                short8 a1 = *reinterpret_cast<const short8*>(&Wv[((ln + 32) * 4 + ck) * 18 + t * 2 + h]);
                #pragma unroll
                for (int rj = 0; rj < 4; ++rj) {
                    unsigned off = ((plane + (unsigned)(yy[rj] + kh) * YP + (unsigned)(xx[rj] + kw)) << 4)
                                   + (h << 3);
                    short8 bb = *reinterpret_cast<const short8*>(Xt + off);
                    acc[0][rj] = __builtin_amdgcn_mfma_f32_32x32x16_bf16(a0, bb, acc[0][rj], 0, 0, 0);
                    acc[1][rj] = __builtin_amdgcn_mfma_f32_32x32x16_bf16(a1, bb, acc[1][rj], 0, 0, 0);
                }
            }
        }
    }

    // store: oc = m*32 + (reg&3) + 8*(reg>>2) + 4*h ; col = pixel p
    #pragma unroll
    for (int m = 0; m < 2; ++m) {
        #pragma unroll
        for (int rj = 0; rj < 4; ++rj) {
            if (!valid[rj]) continue;
            int p = blockIdx.x * 512 + w * 128 + rj * 32 + ln;
            float* ob = out + ((size_t)b * OCn + m * 32 + 4 * h) * NPIX + p;
            #pragma unroll
            for (int reg = 0; reg < 16; ++reg) {
                int row = (reg & 3) + 8 * (reg >> 2);
                ob[(size_t)row * NPIX] = acc[m][rj][reg];
            }
        }
    }
}

// ---------------- fallback (round-5 structure, no ws) ----------------
#define ICP 24
#define WSTRIDE 152
__global__ __launch_bounds__(256, 2)
void adaconv_fallback(const float* __restrict__ x,
                      const float* __restrict__ kb,
                      const float* __restrict__ km,
                      const int* __restrict__ label,
                      const int* __restrict__ epoch,
                      float* __restrict__ out)
{
    __shared__ unsigned short Xs[18][34][ICP];
    __shared__ unsigned short Ws[64][WSTRIDE];

    const int tid = threadIdx.x;
    const int b   = blockIdx.y;
    const int bx  = blockIdx.x & 3;
    const int byy = blockIdx.x >> 2;
    const int x0 = bx * 32, y0 = byy * 16;

    int d = (epoch[0] >= FUSE_EPOCH) ? 0 : label[b];
    d &= 3;

    const int w    = tid >> 6;
    const int lane = tid & 63;
    const int ln   = lane & 31;
    const int h    = lane >> 5;

    f32x16 acc[2][4];
    #pragma unroll
    for (int m = 0; m < 2; ++m)
        #pragma unroll
        for (int j = 0; j < 4; ++j)
            #pragma unroll
            for (int k = 0; k < 16; ++k) acc[m][j][k] = 0.f;

    const float* xb = x + (size_t)b * ICn * HH * WW;

    for (int ck = 0; ck < 4; ++ck) {
        const int icb = ck * 16;
        __syncthreads();
        for (int idx = tid; idx < 18 * 34 * 16; idx += 256) {
            int ic  = idx / 612;
            int rem = idx - ic * 612;
            int r   = rem / 34;
            int c   = rem - r * 34;
            int gy = y0 - 1 + r, gx = x0 - 1 + c;
            float v = 0.f;
            if ((unsigned)gy < HH && (unsigned)gx < WW)
                v = xb[(size_t)(icb + ic) * (HH * WW) + gy * WW + gx];
            Xs[r][c][ic] = f2bf(v);
        }
        for (int i = tid; i < 9216; i += 256) {
            int ic_ = i & 15;
            int tt  = (i >> 4) % 9;
            int oc  = i / 144;
            int ic  = icb + ic_;
            Ws[oc][tt * 16 + ic_] = f2bf(kb[(oc * ICn + ic) * 9 + tt] * km[(d * ICn + ic) * 9 + tt]);
        }
        __syncthreads();
        #pragma unroll
        for (int kh = 0; kh < 3; ++kh)
            #pragma unroll
            for (int kw = 0; kw < 3; ++kw) {
                const int t = kh * 3 + kw;
                short8 a0 = *reinterpret_cast<const short8*>(&Ws[ln][t * 16 + h * 8]);
                short8 a1 = *reinterpret_cast<const short8*>(&Ws[32 + ln][t * 16 + h * 8]);
                #pragma unroll
                for (int rj = 0; rj < 4; ++rj) {
                    short8 bb = *reinterpret_cast<const short8*>(&Xs[4 * w + rj + kh][ln + kw][h * 8]);
                    acc[0][rj] = __builtin_amdgcn_mfma_f32_32x32x16_bf16(a0, bb, acc[0][rj], 0, 0, 0);
                    acc[1][rj] = __builtin_amdgcn_mfma_f32_32x32x16_bf16(a1, bb, acc[1][rj], 0, 0, 0);
                }
            }
    }

    const int xg = x0 + ln;
    if (xg < WW) {
        #pragma unroll
        for (int m = 0; m < 2; ++m)
            #pragma unroll
            for (int rj = 0; rj < 4; ++rj) {
                const int yg = y0 + 4 * w + rj;
                #pragma unroll
                for (int reg = 0; reg < 16; ++reg) {
                    const int row = (reg & 3) + 8 * (reg >> 2) + 4 * h;
                    out[(((size_t)b * OCn + m * 32 + row) * HH + yg) * WW + xg] = acc[m][rj][reg];
                }
            }
    }
}

extern "C" void kernel_launch(void* const* d_in, const int* in_sizes, int n_in,
                              void* d_out, int out_size, void* d_ws, size_t ws_size,
                              hipStream_t stream) {
    const float* x  = (const float*)d_in[0];
    const float* kb = (const float*)d_in[1];
    const float* km = (const float*)d_in[2];
    const int*   lb = (const int*)d_in[3];
    const int*   ep = (const int*)d_in[4];
    float* out = (float*)d_out;

    if (ws_size >= XT_BYTES + WF_BYTES) {
        unsigned short* Xt = (unsigned short*)d_ws;
        unsigned short* wf = (unsigned short*)((char*)d_ws + XT_BYTES);
        fuse_w_kernel<<<(4 * 64 * 576 + 255) / 256, 256, 0, stream>>>(kb, km, wf);
        pad_zero_kernel<<<256, 256, 0, stream>>>(Xt);
        transpose_kernel<<<dim3(2, HH, 64), 256, 0, stream>>>(x, Xt);
        adaconv_main<<<dim3(25, 64), 256, 0, stream>>>(Xt, wf, lb, ep, out);
    } else {
        adaconv_fallback<<<dim3(28, 64), 256, 0, stream>>>(x, kb, km, lb, ep, out);
    }
}

// Round 11
// 207.766 us; speedup vs baseline: 6.8209x; 1.1228x over previous
//
#include <hip/hip_runtime.h>
#include <hip/hip_bf16.h>

// AdaConv2d: per-sample conv, kernel = base * mask[label[b]] (oc-indep mask).
// B=64, IC=OC=64, H=W=112, 3x3, pad 1. fp32 in/out.
//
// Round 10: round 9 was VMEM-latency-bound (MfmaUtil 14%, all pipes idle):
// 216 direct global loads/wave, per-ck L1 footprint 42KB > 32KB L1 -> tap
// revisits hit L2 with ~2 waves/SIMD of TLP. Fix: double-buffered LDS staging
// of the B (Xt) tile via global_load_lds width=16 (per-lane global source,
// linear LDS dest), stage(next) issued before compute(cur) so load latency
// hides under MFMA. B-reads become conflict-free ds_read_b128; A stays in
// global (18KB/ck now L1-resident with B traffic gone).

#define HH 112
#define WW 112
#define ICn 64
#define OCn 64
#define FUSE_EPOCH 9
#define NPIX (HH * WW)
#define YP 114
#define BCH 2048   // 16B chunks per LDS buffer (1824 used, padded for uniform staging)

typedef __attribute__((ext_vector_type(8)))  short  short8;
typedef __attribute__((ext_vector_type(8)))  unsigned short bf8;
typedef __attribute__((ext_vector_type(4)))  unsigned short bf4;
typedef __attribute__((ext_vector_type(16))) float  f32x16;
typedef unsigned int u32;

#define XT_ELEMS ((size_t)64 * 4 * YP * YP * 16)
#define XT_BYTES (XT_ELEMS * 2)
#define WF_BYTES ((size_t)4 * 64 * 576 * 2)

static __device__ __forceinline__ unsigned short f2bf(float v) {
    __hip_bfloat16 hb = __float2bfloat16(v);
    return *reinterpret_cast<unsigned short*>(&hb);
}

static __device__ __forceinline__ void gload16(const unsigned short* g, unsigned short* l) {
    __builtin_amdgcn_global_load_lds(
        (const __attribute__((address_space(1))) u32*)g,
        (__attribute__((address_space(3))) u32*)l, 16, 0, 0);
}

// ---------------- fused weights: wf[d][oc][ck][tap][ic'] ----------------
__global__ __launch_bounds__(256)
void fuse_w_kernel(const float* __restrict__ kb, const float* __restrict__ km,
                   unsigned short* __restrict__ wf)
{
    int idx = blockIdx.x * 256 + threadIdx.x;
    if (idx >= 4 * 64 * 576) return;
    int ic_ = idx & 15;
    int r = idx >> 4;
    int t = r % 9; r /= 9;
    int ch = r & 3; r >>= 2;
    int oc = r & 63;
    int d = r >> 6;
    int ic = ch * 16 + ic_;
    wf[idx] = f2bf(kb[(oc * ICn + ic) * 9 + t] * km[(d * ICn + ic) * 9 + t]);
}

// ---------------- zero the halo of each (b,ck) plane ----------------
__global__ __launch_bounds__(256)
void pad_zero_kernel(unsigned short* __restrict__ Xt)
{
    const int plane = blockIdx.x;   // 0..255 = b*4+ck
    const int tid = threadIdx.x;
    const size_t base = (size_t)plane * YP * YP * 16;
    const bf8 z = bf8{0,0,0,0,0,0,0,0};
    for (int i = tid; i < YP * 2; i += 256) {
        *reinterpret_cast<bf8*>(Xt + base + (size_t)i * 8) = z;
        *reinterpret_cast<bf8*>(Xt + base + (size_t)113 * YP * 16 + (size_t)i * 8) = z;
    }
    for (int i = tid; i < 112 * 2 * 2; i += 256) {
        int j = i & 1, col = (i >> 1) & 1, yp = 1 + (i >> 2);
        size_t off = base + ((size_t)yp * YP + col * 113) * 16 + (size_t)j * 8;
        *reinterpret_cast<bf8*>(Xt + off) = z;
    }
}

// ---- transpose x[b][ic][y][x] fp32 -> Xt[b][ic/16][y+1][x+1][ic%16] bf16 ----
__global__ __launch_bounds__(256, 4)
void transpose_kernel(const float* __restrict__ x, unsigned short* __restrict__ Xt)
{
    __shared__ unsigned short T[56][68];
    const int tid = threadIdx.x;
    const int xh = blockIdx.x;      // 0..1 -> x0 = 0,56
    const int y  = blockIdx.y;      // 0..111
    const int b  = blockIdx.z;      // 0..63
    const int x0 = xh * 56;

    for (int i = tid; i < 64 * 14; i += 256) {       // 64 ic x 14 float4
        int ic = i / 14, c4 = i - ic * 14;
        const float4* p = reinterpret_cast<const float4*>(
            x + (((size_t)b * ICn + ic) * HH + y) * WW + x0 + c4 * 4);
        float4 v = *p;
        T[c4 * 4 + 0][ic] = f2bf(v.x);
        T[c4 * 4 + 1][ic] = f2bf(v.y);
        T[c4 * 4 + 2][ic] = f2bf(v.z);
        T[c4 * 4 + 3][ic] = f2bf(v.w);
    }
    __syncthreads();
    for (int i = tid; i < 56 * 16; i += 256) {       // 56 x  x 16 bf4
        int xx = i >> 4, k = i & 15;
        bf4 w = *reinterpret_cast<bf4*>(&T[xx][k * 4]);
        int ck = k >> 2, q = k & 3;
        *reinterpret_cast<bf4*>(
            Xt + ((((size_t)b * 4 + ck) * YP + y + 1) * YP + (x0 + xx + 1)) * 16 + q * 4) = w;
    }
}

// ---------------- main: implicit GEMM, LDS double-buffered B ----------------
__global__ __launch_bounds__(256, 2)
void adaconv_main(const unsigned short* __restrict__ Xt,
                  const unsigned short* __restrict__ wf,
                  const int* __restrict__ label,
                  const int* __restrict__ epoch,
                  float* __restrict__ out)
{
    __shared__ unsigned short Bs[2][BCH * 8];   // 2 x 32 KiB

    const int tid  = threadIdx.x;
    const int b    = blockIdx.y;
    const int w    = tid >> 6;
    const int lane = tid & 63;
    const int ln   = lane & 31;
    const int h    = lane >> 5;

    int d = (epoch[0] >= FUSE_EPOCH) ? 0 : label[b];
    d &= 3;

    const int p0 = blockIdx.x * 512;
    const int r0 = p0 / WW;            // first padded row staged

    f32x16 acc[2][4];
    #pragma unroll
    for (int m = 0; m < 2; ++m)
        #pragma unroll
        for (int rj = 0; rj < 4; ++rj)
            #pragma unroll
            for (int k = 0; k < 16; ++k) acc[m][rj][k] = 0.f;

    // per-lane pixel coords and LDS element bases (per rj)
    int eb[4];
    bool valid[4];
    int pp[4];
    #pragma unroll
    for (int rj = 0; rj < 4; ++rj) {
        int p = p0 + w * 128 + rj * 32 + ln;
        valid[rj] = (p < NPIX);
        pp[rj] = p;
        int pc = valid[rj] ? p : (NPIX - 1);
        int yy = pc / WW;
        int xx = pc - yy * WW;
        int ry = yy - r0;              // 0..5
        eb[rj] = ((ry * 2 + h) * YP + xx) * 8;
    }

    const bf8* Wv = reinterpret_cast<const bf8*>(wf) + (size_t)d * 64 * 72;
    // Wv index: (oc*4 + ck)*18 + t*2 + h

    // ---- staging: 2048 chunks of 16B -> Bs[buf]; chunk c = (row*2+h)*114+px ----
    auto stage = [&](int buf, int ck) {
        const size_t plane = ((size_t)b * 4 + ck) * (YP * YP);
        #pragma unroll
        for (int r = 0; r < 8; ++r) {
            int c = r * 256 + tid;
            int cc = c < 1824 ? c : 1823;          // pad chunks: dup source
            int row = cc / 228;
            int rem = cc - row * 228;
            int hh  = rem / YP;
            int px  = rem - hh * YP;
            int yp  = r0 + row; if (yp > 113) yp = 113;
            const unsigned short* g = Xt + (plane + (size_t)yp * YP + px) * 16 + hh * 8;
            unsigned short* l = &Bs[buf][(size_t)(r * 256 + w * 64) * 8];  // wave-uniform base
            gload16(g, l);
        }
    };

    stage(0, 0);
    __syncthreads();

    for (int ck = 0; ck < 4; ++ck) {
        const int cur = ck & 1;
        if (ck < 3) stage(cur ^ 1, ck + 1);

        #pragma unroll
        for (int kh = 0; kh < 3; ++kh) {
            #pragma unroll
            for (int kw = 0; kw < 3; ++kw) {
                const int t = kh * 3 + kw;
                short8 a0 = *reinterpret_cast<const short8*>(&Wv[(ln * 4 + ck) * 18 + t * 2 + h]);
                short8 a1 = *reinterpret_cast<const short8*>(&Wv[((ln + 32) * 4 + ck) * 18 + t * 2 + h]);
                #pragma unroll
                for (int rj = 0; rj < 4; ++rj) {
                    short8 bb = *reinterpret_cast<const short8*>(
                        &Bs[cur][eb[rj] + kh * (2 * YP * 8) + kw * 8]);
                    acc[0][rj] = __builtin_amdgcn_mfma_f32_32x32x16_bf16(a0, bb, acc[0][rj], 0, 0, 0);
                    acc[1][rj] = __builtin_amdgcn_mfma_f32_32x32x16_bf16(a1, bb, acc[1][rj], 0, 0, 0);
                }
            }
        }
        __syncthreads();   // drains stage loads; guards WAR on Bs[cur^1]
    }

    // store: oc = m*32 + (reg&3) + 8*(reg>>2) + 4*h ; col = pixel p
    #pragma unroll
    for (int m = 0; m < 2; ++m) {
        #pragma unroll
        for (int rj = 0; rj < 4; ++rj) {
            if (!valid[rj]) continue;
            float* ob = out + ((size_t)b * OCn + m * 32 + 4 * h) * NPIX + pp[rj];
            #pragma unroll
            for (int reg = 0; reg < 16; ++reg) {
                int row = (reg & 3) + 8 * (reg >> 2);
                ob[(size_t)row * NPIX] = acc[m][rj][reg];
            }
        }
    }
}

// ---------------- fallback (round-5 structure, no ws) ----------------
#define ICP 24
#define WSTRIDE 152
__global__ __launch_bounds__(256, 2)
void adaconv_fallback(const float* __restrict__ x,
                      const float* __restrict__ kb,
                      const float* __restrict__ km,
                      const int* __restrict__ label,
                      const int* __restrict__ epoch,
                      float* __restrict__ out)
{
    __shared__ unsigned short Xs[18][34][ICP];
    __shared__ unsigned short Ws[64][WSTRIDE];

    const int tid = threadIdx.x;
    const int b   = blockIdx.y;
    const int bx  = blockIdx.x & 3;
    const int byy = blockIdx.x >> 2;
    const int x0 = bx * 32, y0 = byy * 16;

    int d = (epoch[0] >= FUSE_EPOCH) ? 0 : label[b];
    d &= 3;

    const int w    = tid >> 6;
    const int lane = tid & 63;
    const int ln   = lane & 31;
    const int h    = lane >> 5;

    f32x16 acc[2][4];
    #pragma unroll
    for (int m = 0; m < 2; ++m)
        #pragma unroll
        for (int j = 0; j < 4; ++j)
            #pragma unroll
            for (int k = 0; k < 16; ++k) acc[m][j][k] = 0.f;

    const float* xb = x + (size_t)b * ICn * HH * WW;

    for (int ck = 0; ck < 4; ++ck) {
        const int icb = ck * 16;
        __syncthreads();
        for (int idx = tid; idx < 18 * 34 * 16; idx += 256) {
            int ic  = idx / 612;
            int rem = idx - ic * 612;
            int r   = rem / 34;
            int c   = rem - r * 34;
            int gy = y0 - 1 + r, gx = x0 - 1 + c;
            float v = 0.f;
            if ((unsigned)gy < HH && (unsigned)gx < WW)
                v = xb[(size_t)(icb + ic) * (HH * WW) + gy * WW + gx];
            Xs[r][c][ic] = f2bf(v);
        }
        for (int i = tid; i < 9216; i += 256) {
            int ic_ = i & 15;
            int tt  = (i >> 4) % 9;
            int oc  = i / 144;
            int ic  = icb + ic_;
            Ws[oc][tt * 16 + ic_] = f2bf(kb[(oc * ICn + ic) * 9 + tt] * km[(d * ICn + ic) * 9 + tt]);
        }
        __syncthreads();
        #pragma unroll
        for (int kh = 0; kh < 3; ++kh)
            #pragma unroll
            for (int kw = 0; kw < 3; ++kw) {
                const int t = kh * 3 + kw;
                short8 a0 = *reinterpret_cast<const short8*>(&Ws[ln][t * 16 + h * 8]);
                short8 a1 = *reinterpret_cast<const short8*>(&Ws[32 + ln][t * 16 + h * 8]);
                #pragma unroll
                for (int rj = 0; rj < 4; ++rj) {
                    short8 bb = *reinterpret_cast<const short8*>(&Xs[4 * w + rj + kh][ln + kw][h * 8]);
                    acc[0][rj] = __builtin_amdgcn_mfma_f32_32x32x16_bf16(a0, bb, acc[0][rj], 0, 0, 0);
                    acc[1][rj] = __builtin_amdgcn_mfma_f32_32x32x16_bf16(a1, bb, acc[1][rj], 0, 0, 0);
                }
            }
    }

    const int xg = x0 + ln;
    if (xg < WW) {
        #pragma unroll
        for (int m = 0; m < 2; ++m)
            #pragma unroll
            for (int rj = 0; rj < 4; ++rj) {
                const int yg = y0 + 4 * w + rj;
                #pragma unroll
                for (int reg = 0; reg < 16; ++reg) {
                    const int row = (reg & 3) + 8 * (reg >> 2) + 4 * h;
                    out[(((size_t)b * OCn + m * 32 + row) * HH + yg) * WW + xg] = acc[m][rj][reg];
                }
            }
    }
}

extern "C" void kernel_launch(void* const* d_in, const int* in_sizes, int n_in,
                              void* d_out, int out_size, void* d_ws, size_t ws_size,
                              hipStream_t stream) {
    const float* x  = (const float*)d_in[0];
    const float* kb = (const float*)d_in[1];
    const float* km = (const float*)d_in[2];
    const int*   lb = (const int*)d_in[3];
    const int*   ep = (const int*)d_in[4];
    float* out = (float*)d_out;

    if (ws_size >= XT_BYTES + WF_BYTES) {
        unsigned short* Xt = (unsigned short*)d_ws;
        unsigned short* wf = (unsigned short*)((char*)d_ws + XT_BYTES);
        fuse_w_kernel<<<(4 * 64 * 576 + 255) / 256, 256, 0, stream>>>(kb, km, wf);
        pad_zero_kernel<<<256, 256, 0, stream>>>(Xt);
        transpose_kernel<<<dim3(2, HH, 64), 256, 0, stream>>>(x, Xt);
        adaconv_main<<<dim3(25, 64), 256, 0, stream>>>(Xt, wf, lb, ep, out);
    } else {
        adaconv_fallback<<<dim3(28, 64), 256, 0, stream>>>(x, kb, km, lb, ep, out);
    }
}

// Round 12
// 189.742 us; speedup vs baseline: 7.4688x; 1.0950x over previous
//
#include <hip/hip_runtime.h>
#include <hip/hip_bf16.h>

// AdaConv2d: per-sample conv, kernel = base * mask[label[b]] (oc-indep mask).
// B=64, IC=OC=64, H=W=112, 3x3, pad 1. fp32 in/out.
//
// Round 11: round 10 was dependency-latency-bound (MfmaUtil 17%, all pipes
// idle): per tap 4 ds_reads + 2 scattered A-gathers (64 lines/instr!) feed
// MFMAs directly. Fix: (1) 2D wave tile (4 rows x 32 px) -> 36 B-fragments/ck
// collapse to 18 distinct, register-cached, batch-issued; (2) weights
// re-laid out wf2[d][ck][t][h][oc][8ic] -> A-loads are 2x512B contiguous;
// (3) LDS tile 2x20KB, same stage-ahead double buffer.

#define HH 112
#define WW 112
#define ICn 64
#define OCn 64
#define FUSE_EPOCH 9
#define NPIX (HH * WW)
#define YP 114

typedef __attribute__((ext_vector_type(8)))  short  short8;
typedef __attribute__((ext_vector_type(8)))  unsigned short bf8;
typedef __attribute__((ext_vector_type(4)))  unsigned short bf4;
typedef __attribute__((ext_vector_type(16))) float  f32x16;
typedef unsigned int u32;

#define XT_ELEMS ((size_t)64 * 4 * YP * YP * 16)
#define XT_BYTES (XT_ELEMS * 2)
#define WF_BYTES ((size_t)4 * 64 * 576 * 2)

static __device__ __forceinline__ unsigned short f2bf(float v) {
    __hip_bfloat16 hb = __float2bfloat16(v);
    return *reinterpret_cast<unsigned short*>(&hb);
}

static __device__ __forceinline__ void gload16(const unsigned short* g, unsigned short* l) {
    __builtin_amdgcn_global_load_lds(
        (const __attribute__((address_space(1))) u32*)g,
        (__attribute__((address_space(3))) u32*)l, 16, 0, 0);
}

// -------- fused weights: wf2[d][ck][t][h][oc][8e], ic = ck*16+h*8+e --------
__global__ __launch_bounds__(256)
void fuse_w_kernel(const float* __restrict__ kb, const float* __restrict__ km,
                   unsigned short* __restrict__ wf2)
{
    int idx = blockIdx.x * 256 + threadIdx.x;
    if (idx >= 4 * 4 * 9 * 2 * 64 * 8) return;
    int e  = idx & 7;
    int oc = (idx >> 3) & 63;
    int h  = (idx >> 9) & 1;
    int r  = idx >> 10;          // t + 9*(ck + 4*d)
    int t  = r % 9; r /= 9;
    int ck = r & 3;
    int d  = r >> 2;
    int ic = ck * 16 + h * 8 + e;
    wf2[idx] = f2bf(kb[(oc * ICn + ic) * 9 + t] * km[(d * ICn + ic) * 9 + t]);
}

// ---------------- zero the halo of each (b,ck) plane ----------------
__global__ __launch_bounds__(256)
void pad_zero_kernel(unsigned short* __restrict__ Xt)
{
    const int plane = blockIdx.x;   // 0..255 = b*4+ck
    const int tid = threadIdx.x;
    const size_t base = (size_t)plane * YP * YP * 16;
    const bf8 z = bf8{0,0,0,0,0,0,0,0};
    for (int i = tid; i < YP * 2; i += 256) {
        *reinterpret_cast<bf8*>(Xt + base + (size_t)i * 8) = z;
        *reinterpret_cast<bf8*>(Xt + base + (size_t)113 * YP * 16 + (size_t)i * 8) = z;
    }
    for (int i = tid; i < 112 * 2 * 2; i += 256) {
        int j = i & 1, col = (i >> 1) & 1, yp = 1 + (i >> 2);
        size_t off = base + ((size_t)yp * YP + col * 113) * 16 + (size_t)j * 8;
        *reinterpret_cast<bf8*>(Xt + off) = z;
    }
}

// ---- transpose x[b][ic][y][x] fp32 -> Xt[b][ic/16][y+1][x+1][ic%16] bf16 ----
__global__ __launch_bounds__(256, 4)
void transpose_kernel(const float* __restrict__ x, unsigned short* __restrict__ Xt)
{
    __shared__ unsigned short T[56][68];
    const int tid = threadIdx.x;
    const int xh = blockIdx.x;      // 0..1 -> x0 = 0,56
    const int y  = blockIdx.y;      // 0..111
    const int b  = blockIdx.z;      // 0..63
    const int x0 = xh * 56;

    for (int i = tid; i < 64 * 14; i += 256) {       // 64 ic x 14 float4
        int ic = i / 14, c4 = i - ic * 14;
        const float4* p = reinterpret_cast<const float4*>(
            x + (((size_t)b * ICn + ic) * HH + y) * WW + x0 + c4 * 4);
        float4 v = *p;
        T[c4 * 4 + 0][ic] = f2bf(v.x);
        T[c4 * 4 + 1][ic] = f2bf(v.y);
        T[c4 * 4 + 2][ic] = f2bf(v.z);
        T[c4 * 4 + 3][ic] = f2bf(v.w);
    }
    __syncthreads();
    for (int i = tid; i < 56 * 16; i += 256) {       // 56 x  x 16 bf4
        int xx = i >> 4, k = i & 15;
        bf4 w = *reinterpret_cast<bf4*>(&T[xx][k * 4]);
        int ck = k >> 2, q = k & 3;
        *reinterpret_cast<bf4*>(
            Xt + ((((size_t)b * 4 + ck) * YP + y + 1) * YP + (x0 + xx + 1)) * 16 + q * 4) = w;
    }
}

// ---------------- main: implicit GEMM, 2D tiles, LDS dbuf B ----------------
__global__ __launch_bounds__(256, 2)
void adaconv_main(const unsigned short* __restrict__ Xt,
                  const unsigned short* __restrict__ wf2,
                  const int* __restrict__ label,
                  const int* __restrict__ epoch,
                  float* __restrict__ out)
{
    __shared__ unsigned short Bs[2][1280 * 8];   // 2 x 20 KiB

    const int tid  = threadIdx.x;
    const int b    = blockIdx.y;
    const int bx   = blockIdx.x & 3;     // x-tile: x0 = 0,32,64,96
    const int byy  = blockIdx.x >> 2;    // y-tile: 0..6
    const int x0 = bx * 32, y0 = byy * 16;
    const int w    = tid >> 6;
    const int lane = tid & 63;
    const int ln   = lane & 31;
    const int h    = lane >> 5;

    int d = (epoch[0] >= FUSE_EPOCH) ? 0 : label[b];
    d &= 3;

    f32x16 acc[2][4];
    #pragma unroll
    for (int m = 0; m < 2; ++m)
        #pragma unroll
        for (int rj = 0; rj < 4; ++rj)
            #pragma unroll
            for (int k = 0; k < 16; ++k) acc[m][rj][k] = 0.f;

    const unsigned short* Wd = wf2 + (size_t)d * 4 * 9 * 1024;
    const int aoff = h * 512 + ln * 8;   // (h*64 + oc)*8 for oc=ln

    // ---- staging: 1224 chunks of 16B; chunk c = (lr*2+hh)*34 + px ----
    auto stage = [&](int buf, int ck) {
        const size_t plane = ((size_t)b * 4 + ck) * (YP * YP);
        #pragma unroll
        for (int r = 0; r < 5; ++r) {
            int c = r * 256 + tid;
            int cc = c < 1224 ? c : 1223;
            int lr  = cc / 68;
            int rem = cc - lr * 68;
            int hh  = rem / 34;
            int px  = rem - hh * 34;
            int yp  = y0 + lr;                       // <= 113 always
            int xp  = x0 + px; if (xp > 113) xp = 113;  // tile 3 clamp (zero col)
            const unsigned short* g = Xt + (plane + (size_t)yp * YP + xp) * 16 + hh * 8;
            unsigned short* l = &Bs[buf][(size_t)(r * 256 + w * 64) * 8];  // wave-uniform
            gload16(g, l);
        }
    };

    stage(0, 0);
    __syncthreads();

    for (int ck = 0; ck < 4; ++ck) {
        const int cur = ck & 1;
        if (ck < 3) stage(cur ^ 1, ck + 1);

        // ---- register-cache the 18 distinct B fragments (rows 4w..4w+5, kw 0..2) ----
        short8 frag[6][3];
        #pragma unroll
        for (int r6 = 0; r6 < 6; ++r6)
            #pragma unroll
            for (int kw = 0; kw < 3; ++kw)
                frag[r6][kw] = *reinterpret_cast<const short8*>(
                    &Bs[cur][(size_t)(((4 * w + r6) * 2 + h) * 34 + ln + kw) * 8]);

        const unsigned short* Wt = Wd + (size_t)ck * 9 * 1024;
        #pragma unroll
        for (int kh = 0; kh < 3; ++kh) {
            #pragma unroll
            for (int kw = 0; kw < 3; ++kw) {
                const int t = kh * 3 + kw;
                short8 a0 = *reinterpret_cast<const short8*>(Wt + t * 1024 + aoff);
                short8 a1 = *reinterpret_cast<const short8*>(Wt + t * 1024 + aoff + 256);
                #pragma unroll
                for (int rj = 0; rj < 4; ++rj) {
                    acc[0][rj] = __builtin_amdgcn_mfma_f32_32x32x16_bf16(a0, frag[rj + kh][kw], acc[0][rj], 0, 0, 0);
                    acc[1][rj] = __builtin_amdgcn_mfma_f32_32x32x16_bf16(a1, frag[rj + kh][kw], acc[1][rj], 0, 0, 0);
                }
            }
        }
        __syncthreads();   // drains stage loads; WAR guard on Bs
    }

    // ---- store: oc = m*32 + (reg&3) + 8*(reg>>2) + 4*h ----
    const int xg = x0 + ln;
    if (xg < WW) {
        #pragma unroll
        for (int m = 0; m < 2; ++m) {
            #pragma unroll
            for (int rj = 0; rj < 4; ++rj) {
                const int yg = y0 + 4 * w + rj;
                float* ob = out + ((size_t)b * OCn + m * 32 + 4 * h) * NPIX + (size_t)yg * WW + xg;
                #pragma unroll
                for (int reg = 0; reg < 16; ++reg) {
                    int row = (reg & 3) + 8 * (reg >> 2);
                    ob[(size_t)row * NPIX] = acc[m][rj][reg];
                }
            }
        }
    }
}

// ---------------- fallback (round-5 structure, no ws) ----------------
#define ICP 24
#define WSTRIDE 152
__global__ __launch_bounds__(256, 2)
void adaconv_fallback(const float* __restrict__ x,
                      const float* __restrict__ kb,
                      const float* __restrict__ km,
                      const int* __restrict__ label,
                      const int* __restrict__ epoch,
                      float* __restrict__ out)
{
    __shared__ unsigned short Xs[18][34][ICP];
    __shared__ unsigned short Ws[64][WSTRIDE];

    const int tid = threadIdx.x;
    const int b   = blockIdx.y;
    const int bx  = blockIdx.x & 3;
    const int byy = blockIdx.x >> 2;
    const int x0 = bx * 32, y0 = byy * 16;

    int d = (epoch[0] >= FUSE_EPOCH) ? 0 : label[b];
    d &= 3;

    const int w    = tid >> 6;
    const int lane = tid & 63;
    const int ln   = lane & 31;
    const int h    = lane >> 5;

    f32x16 acc[2][4];
    #pragma unroll
    for (int m = 0; m < 2; ++m)
        #pragma unroll
        for (int j = 0; j < 4; ++j)
            #pragma unroll
            for (int k = 0; k < 16; ++k) acc[m][j][k] = 0.f;

    const float* xb = x + (size_t)b * ICn * HH * WW;

    for (int ck = 0; ck < 4; ++ck) {
        const int icb = ck * 16;
        __syncthreads();
        for (int idx = tid; idx < 18 * 34 * 16; idx += 256) {
            int ic  = idx / 612;
            int rem = idx - ic * 612;
            int r   = rem / 34;
            int c   = rem - r * 34;
            int gy = y0 - 1 + r, gx = x0 - 1 + c;
            float v = 0.f;
            if ((unsigned)gy < HH && (unsigned)gx < WW)
                v = xb[(size_t)(icb + ic) * (HH * WW) + gy * WW + gx];
            Xs[r][c][ic] = f2bf(v);
        }
        for (int i = tid; i < 9216; i += 256) {
            int ic_ = i & 15;
            int tt  = (i >> 4) % 9;
            int oc  = i / 144;
            int ic  = icb + ic_;
            Ws[oc][tt * 16 + ic_] = f2bf(kb[(oc * ICn + ic) * 9 + tt] * km[(d * ICn + ic) * 9 + tt]);
        }
        __syncthreads();
        #pragma unroll
        for (int kh = 0; kh < 3; ++kh)
            #pragma unroll
            for (int kw = 0; kw < 3; ++kw) {
                const int t = kh * 3 + kw;
                short8 a0 = *reinterpret_cast<const short8*>(&Ws[ln][t * 16 + h * 8]);
                short8 a1 = *reinterpret_cast<const short8*>(&Ws[32 + ln][t * 16 + h * 8]);
                #pragma unroll
                for (int rj = 0; rj < 4; ++rj) {
                    short8 bb = *reinterpret_cast<const short8*>(&Xs[4 * w + rj + kh][ln + kw][h * 8]);
                    acc[0][rj] = __builtin_amdgcn_mfma_f32_32x32x16_bf16(a0, bb, acc[0][rj], 0, 0, 0);
                    acc[1][rj] = __builtin_amdgcn_mfma_f32_32x32x16_bf16(a1, bb, acc[1][rj], 0, 0, 0);
                }
            }
    }

    const int xg = x0 + ln;
    if (xg < WW) {
        #pragma unroll
        for (int m = 0; m < 2; ++m)
            #pragma unroll
            for (int rj = 0; rj < 4; ++rj) {
                const int yg = y0 + 4 * w + rj;
                #pragma unroll
                for (int reg = 0; reg < 16; ++reg) {
                    const int row = (reg & 3) + 8 * (reg >> 2) + 4 * h;
                    out[(((size_t)b * OCn + m * 32 + row) * HH + yg) * WW + xg] = acc[m][rj][reg];
                }
            }
    }
}

extern "C" void kernel_launch(void* const* d_in, const int* in_sizes, int n_in,
                              void* d_out, int out_size, void* d_ws, size_t ws_size,
                              hipStream_t stream) {
    const float* x  = (const float*)d_in[0];
    const float* kb = (const float*)d_in[1];
    const float* km = (const float*)d_in[2];
    const int*   lb = (const int*)d_in[3];
    const int*   ep = (const int*)d_in[4];
    float* out = (float*)d_out;

    if (ws_size >= XT_BYTES + WF_BYTES) {
        unsigned short* Xt  = (unsigned short*)d_ws;
        unsigned short* wf2 = (unsigned short*)((char*)d_ws + XT_BYTES);
        fuse_w_kernel<<<576, 256, 0, stream>>>(kb, km, wf2);
        pad_zero_kernel<<<256, 256, 0, stream>>>(Xt);
        transpose_kernel<<<dim3(2, HH, 64), 256, 0, stream>>>(x, Xt);
        adaconv_main<<<dim3(28, 64), 256, 0, stream>>>(Xt, wf2, lb, ep, out);
    } else {
        adaconv_fallback<<<dim3(28, 64), 256, 0, stream>>>(x, kb, km, lb, ep, out);
    }
}